// Round 4
// baseline (41.809 us; speedup 1.0000x reference)
//
#include <hip/hip_runtime.h>
#include <math.h>

// 32 fixed taps from the problem definition (TAPS_INT), as exact fp32 values.
__device__ __constant__ const float TAPS[32] = {
    -12.f,  -34.f,  -56.f,  -42.f,   18.f,  120.f,  260.f,  380.f,
    400.f,  290.f,   60.f, -210.f, -430.f, -500.f, -380.f, -120.f,
    180.f,  430.f,  540.f,  480.f,  280.f,   20.f, -220.f, -370.f,
   -400.f, -310.f, -150.f,   10.f,  120.f,  160.f,  130.f,   60.f
};

#define SCALE_INV (1.0f / 65536.0f)
#define TILE 2048            // floats per block
#define HALO 32
#define NT   512             // threads per block
#define NF4  ((TILE + HALO) / 4)   // 520 float4s staged per block

// TILE=2048 / 512 threads / 4 outputs-per-thread makes every access pattern
// naturally optimal with NO swizzle:
//   stage:  s_in[tid]     <- x4[dense]   (lane-consecutive, conflict-free)
//   window: s_in[tid + j] (lane-consecutive per j, conflict-free)
//   store:  y4[tile4+tid] (one dense float4 per thread, no s_out round-trip)
__global__ __launch_bounds__(NT)
void fir32_lds4(const float* __restrict__ x, float* __restrict__ y, int n) {
    __shared__ float4 s_in[NF4];

    const int tid = threadIdx.x;
    const long tile4 = (long)blockIdx.x * (TILE / 4);
    const long base4 = tile4 - (HALO / 4);   // first staged float4 (may be <0 for block 0)
    const long n4 = (long)n >> 2;
    const float4* x4 = reinterpret_cast<const float4*>(x);

    // ---- Phase 1: dense coalesced staging of x[tile-32 .. tile+2047] ----
    {
        long g0 = base4 + tid;
        float4 v = make_float4(0.f, 0.f, 0.f, 0.f);
        if (g0 >= 0 && g0 < n4) v = x4[g0];
        s_in[tid] = v;
        if (tid < NF4 - NT) {               // 8 halo float4s
            long g1 = g0 + NT;
            float4 h = make_float4(0.f, 0.f, 0.f, 0.f);
            if (g1 >= 0 && g1 < n4) h = x4[g1];
            s_in[tid + NT] = h;
        }
    }
    __syncthreads();

    // ---- Phase 2: 36-float window from LDS (9 lane-consecutive float4 reads) ----
    float w[36];
    #pragma unroll
    for (int j = 0; j < 9; ++j) {
        float4 t = s_in[tid + j];           // float4 index base4 + tid + j
        w[4 * j + 0] = t.x;
        w[4 * j + 1] = t.y;
        w[4 * j + 2] = t.z;
        w[4 * j + 3] = t.w;
    }

    // Outputs 0..31 are defined as exactly 0 (block 0, threads 0..7).
    const bool zero_head = (blockIdx.x == 0) && (tid < 8);

    float acc[4];
    #pragma unroll
    for (int j = 0; j < 4; ++j) {
        float a = 0.0f;
        #pragma unroll
        for (int k = 0; k < 32; ++k) {
            // y[4*(tile4+tid) + j] needs x[m-k] == w[32 + j - k]
            a = fmaf(w[32 + j - k], TAPS[k], a);
        }
        acc[j] = zero_head ? 0.0f : floorf(a * SCALE_INV);
    }

    // ---- Phase 3: one dense float4 store per thread ----
    const long o = tile4 + tid;
    if (o < n4) {
        reinterpret_cast<float4*>(y)[o] =
            make_float4(acc[0], acc[1], acc[2], acc[3]);
    }
}

extern "C" void kernel_launch(void* const* d_in, const int* in_sizes, int n_in,
                              void* d_out, int out_size, void* d_ws, size_t ws_size,
                              hipStream_t stream) {
    const float* x = (const float*)d_in[0];
    float* y = (float*)d_out;
    const int n = in_sizes[0];

    const int grid = (int)(((long)n + TILE - 1) / TILE);  // 8192 blocks for N=2^24
    fir32_lds4<<<dim3(grid), dim3(NT), 0, stream>>>(x, y, n);
}

// Round 5
// 27.437 us; speedup vs baseline: 1.5238x; 1.5238x over previous
//
#include <hip/hip_runtime.h>
#include <math.h>

// 32 fixed taps from the problem definition (TAPS_INT), as exact fp32 values.
__device__ __constant__ const float TAPS[32] = {
    -12.f,  -34.f,  -56.f,  -42.f,   18.f,  120.f,  260.f,  380.f,
    400.f,  290.f,   60.f, -210.f, -430.f, -500.f, -380.f, -120.f,
    180.f,  430.f,  540.f,  480.f,  280.f,   20.f, -220.f, -370.f,
   -400.f, -310.f, -150.f,   10.f,  120.f,  160.f,  130.f,   60.f
};

#define SCALE_INV (1.0f / 65536.0f)

// 8 outputs per thread, pure registers, no LDS.
//  - loads: 10 float4s/thread, lane stride 32B -> every wave load instr is
//    dense (32 cache lines, 2 lanes/line); L1 absorbs the 5x window overlap.
//  - stores: 2 dense float4s/thread.
//  - uniform control flow, predicated head zeroing (outputs 0..31 == 0),
//    no early return after any store.
__global__ __launch_bounds__(256)
void fir32_dense8(const float* __restrict__ x, float* __restrict__ y, int n) {
    const int t = blockIdx.x * blockDim.x + threadIdx.x;  // 8-sample chunk id
    const long n4 = (long)n >> 2;
    const long o4 = 2L * t;                               // first output float4
    if (o4 >= n4) return;                                 // exact grid: never taken

    const float4* x4 = reinterpret_cast<const float4*>(x);
    const bool head = (t < 4);  // outputs 0..31 are defined as exactly 0

    // Window x[8t-32 .. 8t+7] = float4 indices o4-8 .. o4+1 (clamped for the
    // 4 head threads whose results are predicated to zero anyway).
    float w[40];
    #pragma unroll
    for (int c = 0; c < 10; ++c) {
        long i4 = o4 - 8 + c;
        i4 = (i4 < 0) ? 0 : i4;  // head-only clamp; loaded values unused there
        float4 v = x4[i4];
        w[4 * c + 0] = v.x;
        w[4 * c + 1] = v.y;
        w[4 * c + 2] = v.z;
        w[4 * c + 3] = v.w;
    }

    float acc[8];
    #pragma unroll
    for (int j = 0; j < 8; ++j) {
        float a = 0.0f;
        #pragma unroll
        for (int k = 0; k < 32; ++k) {
            // y[8t + j] needs x[m-k] == w[32 + j - k]
            a = fmaf(w[32 + j - k], TAPS[k], a);
        }
        acc[j] = head ? 0.0f : floorf(a * SCALE_INV);
    }

    float4* y4 = reinterpret_cast<float4*>(y);
    y4[o4]     = make_float4(acc[0], acc[1], acc[2], acc[3]);
    y4[o4 + 1] = make_float4(acc[4], acc[5], acc[6], acc[7]);
}

extern "C" void kernel_launch(void* const* d_in, const int* in_sizes, int n_in,
                              void* d_out, int out_size, void* d_ws, size_t ws_size,
                              hipStream_t stream) {
    const float* x = (const float*)d_in[0];
    float* y = (float*)d_out;
    const int n = in_sizes[0];

    const long nthreads = (long)n / 8;                   // 2^21 threads
    const int block = 256;
    const int grid = (int)((nthreads + block - 1) / block);  // 8192 blocks

    fir32_dense8<<<dim3(grid), dim3(block), 0, stream>>>(x, y, n);
}